// Round 1
// baseline (469.596 us; speedup 1.0000x reference)
//
#include <hip/hip_runtime.h>

// RetinaNet decode + per-class NMS (exact reference semantics).
// Pipeline: memset(meta) -> k_map -> k_thresh -> k_compact -> k_nms -> k_fallback
#define NB 8
#define NA 76725
#define NC 80
#define MAXDET 100
#define KSEL 1024          // target top-K per image
#define CAP  2048          // compaction buffer capacity per image
#define HBASE 0x3F7F0000u  // float bits of 0.99609375 — histogram base

__device__ inline unsigned long long shfl_down_u64(unsigned long long v, int o) {
    unsigned lo = (unsigned)v, hi = (unsigned)(v >> 32);
    lo = __shfl_down(lo, o);
    hi = __shfl_down(hi, o);
    return ((unsigned long long)hi << 32) | lo;
}

__device__ inline bool iou_ge_half(float ax1, float ay1, float ax2, float ay2, float aar,
                                   float bx1, float by1, float bx2, float by2, float bar) {
    float xx1 = fmaxf(ax1, bx1), yy1 = fmaxf(ay1, by1);
    float xx2 = fminf(ax2, bx2), yy2 = fminf(ay2, by2);
    float inter = fmaxf(xx2 - xx1, 0.0f) * fmaxf(yy2 - yy1, 0.0f);
    float un = aar + bar - inter;             // commutative add: matches ref exactly
    float iou = (un > 0.0f) ? inter / un : 0.0f;
    return iou >= 0.5f;
}

// ---- Kernel 1: per-anchor map: class max/argmax, box decode, key/box emit, histogram
__global__ __launch_bounds__(256) void k_map(const float* __restrict__ cls,
                                             const float* __restrict__ reg,
                                             const float* __restrict__ anc,
                                             unsigned long long* __restrict__ keys,
                                             unsigned long long* __restrict__ boxes,
                                             unsigned int* __restrict__ hist,
                                             unsigned int* __restrict__ vcnt) {
    __shared__ unsigned int lh[256];
    const int b = blockIdx.y;
    const int a = blockIdx.x * 256 + threadIdx.x;
    lh[threadIdx.x] = 0;
    __syncthreads();

    bool valid = false;
    if (a < NA) {
        const size_t n = (size_t)b * NA + a;
        const float4* cp = reinterpret_cast<const float4*>(cls + n * NC);
        float best = -1.0f; int bc = 0;
#pragma unroll
        for (int j = 0; j < NC / 4; ++j) {
            float4 v = cp[j];
            if (v.x > best) { best = v.x; bc = 4 * j + 0; }
            if (v.y > best) { best = v.y; bc = 4 * j + 1; }
            if (v.z > best) { best = v.z; bc = 4 * j + 2; }
            if (v.w > best) { best = v.w; bc = 4 * j + 3; }
        }
        float4 rg = reinterpret_cast<const float4*>(reg)[n];
        float4 an = reinterpret_cast<const float4*>(anc)[n];
        // decode — _rn intrinsics to forbid FMA contraction (match XLA mul+add)
        float wx = __fsub_rn(an.z, an.x);
        float wy = __fsub_rn(an.w, an.y);
        float cx = __fadd_rn(an.x, __fmul_rn(0.5f, wx));
        float cy = __fadd_rn(an.y, __fmul_rn(0.5f, wy));
        float tx = __fmul_rn(rg.x, 0.1f), ty = __fmul_rn(rg.y, 0.1f);
        float tw = __fmul_rn(rg.z, 0.2f), th = __fmul_rn(rg.w, 0.2f);
        float pw = __fmul_rn(expf(tw), wx);
        float ph = __fmul_rn(expf(th), wy);
        float px = __fadd_rn(__fmul_rn(tx, wx), cx);
        float py = __fadd_rn(__fmul_rn(ty, wy), cy);
        int x1 = (int)__fsub_rn(px, __fmul_rn(0.5f, pw));
        int y1 = (int)__fsub_rn(py, __fmul_rn(0.5f, ph));
        int x2 = (int)__fadd_rn(px, __fmul_rn(0.5f, pw));
        int y2 = (int)__fadd_rn(py, __fmul_rn(0.5f, ph));
        x1 = max(x1, 0); y1 = max(y1, 0); x2 = min(x2, 639); y2 = min(y2, 639);

        unsigned long long bp = (unsigned long long)(unsigned short)(short)x1
                              | ((unsigned long long)(unsigned short)(short)y1 << 16)
                              | ((unsigned long long)(unsigned short)(short)x2 << 32)
                              | ((unsigned long long)(unsigned short)(short)y2 << 48);
        unsigned long long key = 0ull;
        if (best > 0.05f) {  // MIN_SCORE strict
            unsigned sbits = __float_as_uint(best);
            unsigned inv = 0x1FFFFu - (unsigned)a;  // index asc tie-break under desc sort
            key = ((unsigned long long)sbits << 32) | ((unsigned long long)inv << 7)
                | (unsigned)bc;
            valid = true;
            if (sbits >= HBASE) {
                unsigned bin = (sbits - HBASE) >> 8;
                if (bin > 255u) bin = 255u;
                atomicAdd(&lh[bin], 1u);
            }
        }
        keys[n] = key;
        boxes[n] = bp;
    }
    unsigned long long bal = __ballot(valid);
    if ((threadIdx.x & 63) == 0 && bal)
        atomicAdd(&vcnt[b], (unsigned)__popcll(bal));
    __syncthreads();
    if (lh[threadIdx.x]) atomicAdd(&hist[b * 256 + threadIdx.x], lh[threadIdx.x]);
}

// ---- Kernel 2: per-image score-bits threshold from histogram
__global__ void k_thresh(const unsigned int* __restrict__ hist, unsigned int* __restrict__ Tb) {
    int b = threadIdx.x;
    if (b < NB) {
        unsigned cum = 0; int t = -1;
        for (int i = 255; i >= 0; --i) {
            cum += hist[b * 256 + i];
            if (cum >= KSEL) { t = i; break; }
        }
        Tb[b] = (t < 0) ? 0u : (HBASE + ((unsigned)t << 8));
    }
}

// ---- Kernel 3: compact candidates >= threshold into per-image buffers
__global__ __launch_bounds__(256) void k_compact(const unsigned long long* __restrict__ keys,
                                                 const unsigned long long* __restrict__ boxes,
                                                 const unsigned int* __restrict__ Tb,
                                                 unsigned int* __restrict__ cnt,
                                                 ulonglong2* __restrict__ cand) {
    const int b = blockIdx.y;
    const int a = blockIdx.x * 256 + threadIdx.x;
    const unsigned thr = Tb[b];
    bool sel = false;
    unsigned long long key = 0ull;
    size_t n = (size_t)b * NA + a;
    if (a < NA) {
        key = keys[n];
        sel = (key != 0ull) && ((unsigned)(key >> 32) >= thr);
    }
    unsigned long long bal = __ballot(sel);
    int lane = threadIdx.x & 63;
    unsigned base = 0;
    if (lane == 0 && bal) base = atomicAdd(&cnt[b], (unsigned)__popcll(bal));
    base = __shfl(base, 0);
    if (sel) {
        unsigned off = base + (unsigned)__popcll(bal & ((1ull << lane) - 1ull));
        if (off < CAP) {
            ulonglong2 e; e.x = key; e.y = boxes[n];
            cand[(size_t)b * CAP + off] = e;
        }
    }
}

// ---- Kernel 4: per-image bitonic sort (LDS) + greedy NMS walk + emit
__global__ __launch_bounds__(1024) void k_nms(const ulonglong2* __restrict__ cand,
                                              const unsigned int* __restrict__ cnt,
                                              const unsigned int* __restrict__ Tb,
                                              const unsigned int* __restrict__ vcnt,
                                              unsigned int* __restrict__ flag,
                                              float* __restrict__ out) {
    __shared__ unsigned long long sk[CAP];
    __shared__ unsigned long long sb[CAP];
    __shared__ int s_np;
    const int b = blockIdx.x;
    unsigned total = cnt[b];
    bool overflow = total > CAP;
    unsigned m = overflow ? CAP : total;

    for (int i = threadIdx.x; i < CAP; i += 1024) {
        if (i < (int)m) { ulonglong2 e = cand[(size_t)b * CAP + i]; sk[i] = e.x; sb[i] = e.y; }
        else            { sk[i] = 0ull; sb[i] = 0ull; }
    }
    __syncthreads();

    // bitonic sort, descending by key
    for (int k = 2; k <= CAP; k <<= 1) {
        for (int j = k >> 1; j > 0; j >>= 1) {
            for (int i = threadIdx.x; i < CAP; i += 1024) {
                int l = i ^ j;
                if (l > i) {
                    unsigned long long ki = sk[i], kl = sk[l];
                    bool desc = (i & k) == 0;
                    bool sw = desc ? (ki < kl) : (ki > kl);
                    if (sw) {
                        sk[i] = kl; sk[l] = ki;
                        unsigned long long t = sb[i]; sb[i] = sb[l]; sb[l] = t;
                    }
                }
            }
            __syncthreads();
        }
    }

    // greedy walk on wave 0; picked state distributed in registers (2 slots/lane)
    if (threadIdx.x < 64) {
        const int lane = threadIdx.x;
        float q0x1 = 0, q0y1 = 0, q0x2 = 0, q0y2 = 0, q0a = 0; int q0c = -1;
        float q1x1 = 0, q1y1 = 0, q1x2 = 0, q1y2 = 0, q1a = 0; int q1c = -1;
        int np = 0;
        for (int jj = 0; jj < (int)m && np < MAXDET; ++jj) {
            unsigned long long key = sk[jj];
            if (!key) break;
            int ci = (int)(key & 0x7Full);
            unsigned long long bx = sb[jj];
            float x1 = (float)(short)(bx & 0xFFFF);
            float y1 = (float)(short)((bx >> 16) & 0xFFFF);
            float x2 = (float)(short)((bx >> 32) & 0xFFFF);
            float y2 = (float)(short)((bx >> 48) & 0xFFFF);
            float ar = (x2 - x1) * (y2 - y1);
            bool sup = false;
            if (lane < np && q0c == ci)
                sup = iou_ge_half(q0x1, q0y1, q0x2, q0y2, q0a, x1, y1, x2, y2, ar);
            if (64 + lane < np && q1c == ci)
                sup = sup || iou_ge_half(q1x1, q1y1, q1x2, q1y2, q1a, x1, y1, x2, y2, ar);
            if (__ballot(sup) != 0ull) continue;
            int s = np;
            if (s < 64) {
                if (lane == s) {
                    q0x1 = x1; q0y1 = y1; q0x2 = x2; q0y2 = y2; q0a = ar; q0c = ci;
                    out[b * MAXDET + s] = __uint_as_float((unsigned)(key >> 32));
                    out[NB * MAXDET + b * MAXDET + s] = (float)ci;
                    float* ob = out + 2 * NB * MAXDET + (size_t)(b * MAXDET + s) * 4;
                    ob[0] = x1; ob[1] = y1; ob[2] = x2; ob[3] = y2;
                }
            } else {
                if (lane == s - 64) {
                    q1x1 = x1; q1y1 = y1; q1x2 = x2; q1y2 = y2; q1a = ar; q1c = ci;
                    out[b * MAXDET + s] = __uint_as_float((unsigned)(key >> 32));
                    out[NB * MAXDET + b * MAXDET + s] = (float)ci;
                    float* ob = out + 2 * NB * MAXDET + (size_t)(b * MAXDET + s) * 4;
                    ob[0] = x1; ob[1] = y1; ob[2] = x2; ob[3] = y2;
                }
            }
            ++np;
        }
        if (lane == 0) s_np = np;
    }
    __syncthreads();
    int np = s_np;
    // fallback iff candidates were dropped (overflow) or walk exhausted with unseen valid cands
    bool fb = overflow || (np < MAXDET && vcnt[b] > m);
    if (threadIdx.x == 0) flag[b] = fb ? 1u : 0u;
    if (!fb) {
        for (int i = np + (int)threadIdx.x; i < MAXDET; i += 1024) {
            out[b * MAXDET + i] = -1.0f;
            out[NB * MAXDET + b * MAXDET + i] = -1.0f;
            float* ob = out + 2 * NB * MAXDET + (size_t)(b * MAXDET + i) * 4;
            ob[0] = -1.0f; ob[1] = -1.0f; ob[2] = -1.0f; ob[3] = -1.0f;
        }
    }
}

// ---- Kernel 5: exact slow fallback (reference algorithm); no-op unless flag[b]
__global__ __launch_bounds__(1024) void k_fallback(unsigned long long* __restrict__ keys,
                                                   const unsigned long long* __restrict__ boxes,
                                                   const unsigned int* __restrict__ flag,
                                                   float* __restrict__ out) {
    const int b = blockIdx.x;
    if (!flag[b]) return;
    __shared__ unsigned long long wm[16];
    __shared__ unsigned long long gbest;
    unsigned long long* kb = keys + (size_t)b * NA;
    const unsigned long long* bb = boxes + (size_t)b * NA;

    for (int it = 0; it < MAXDET; ++it) {
        unsigned long long best = 0ull;
        for (int i = threadIdx.x; i < NA; i += 1024) {
            unsigned long long k = kb[i];
            if (k > best) best = k;
        }
        for (int o = 32; o > 0; o >>= 1) {
            unsigned long long v = shfl_down_u64(best, o);
            if (v > best) best = v;
        }
        if ((threadIdx.x & 63) == 0) wm[threadIdx.x >> 6] = best;
        __syncthreads();
        if (threadIdx.x == 0) {
            unsigned long long g = wm[0];
            for (int w = 1; w < 16; ++w) if (wm[w] > g) g = wm[w];
            gbest = g;
        }
        __syncthreads();
        best = gbest;
        if (best == 0ull) {
            for (int s = it + (int)threadIdx.x; s < MAXDET; s += 1024) {
                out[b * MAXDET + s] = -1.0f;
                out[NB * MAXDET + b * MAXDET + s] = -1.0f;
                float* ob = out + 2 * NB * MAXDET + (size_t)(b * MAXDET + s) * 4;
                ob[0] = -1.0f; ob[1] = -1.0f; ob[2] = -1.0f; ob[3] = -1.0f;
            }
            break;
        }
        int ci = (int)(best & 0x7Full);
        int a = 0x1FFFF - (int)((best >> 7) & 0x1FFFFull);
        unsigned long long bx = bb[a];
        float x1 = (float)(short)(bx & 0xFFFF);
        float y1 = (float)(short)((bx >> 16) & 0xFFFF);
        float x2 = (float)(short)((bx >> 32) & 0xFFFF);
        float y2 = (float)(short)((bx >> 48) & 0xFFFF);
        float ar = (x2 - x1) * (y2 - y1);
        if (threadIdx.x == 0) {
            out[b * MAXDET + it] = __uint_as_float((unsigned)(best >> 32));
            out[NB * MAXDET + b * MAXDET + it] = (float)ci;
            float* ob = out + 2 * NB * MAXDET + (size_t)(b * MAXDET + it) * 4;
            ob[0] = x1; ob[1] = y1; ob[2] = x2; ob[3] = y2;
        }
        for (int i = threadIdx.x; i < NA; i += 1024) {
            unsigned long long kk = kb[i];
            if (!kk) continue;
            if (kk == best) { kb[i] = 0ull; continue; }
            if ((int)(kk & 0x7Full) != ci) continue;
            unsigned long long ob2 = bb[i];
            float u1 = (float)(short)(ob2 & 0xFFFF);
            float v1 = (float)(short)((ob2 >> 16) & 0xFFFF);
            float u2 = (float)(short)((ob2 >> 32) & 0xFFFF);
            float v2 = (float)(short)((ob2 >> 48) & 0xFFFF);
            float oar = (u2 - u1) * (v2 - v1);
            if (iou_ge_half(x1, y1, x2, y2, ar, u1, v1, u2, v2, oar)) kb[i] = 0ull;
        }
        __syncthreads();
    }
}

extern "C" void kernel_launch(void* const* d_in, const int* in_sizes, int n_in,
                              void* d_out, int out_size, void* d_ws, size_t ws_size,
                              hipStream_t stream) {
    const float* cls = (const float*)d_in[0];
    const float* reg = (const float*)d_in[1];
    const float* anc = (const float*)d_in[2];
    float* out = (float*)d_out;

    const size_t SZ_KEYS = (size_t)NB * NA * 8;               // 4,910,400
    unsigned long long* keys  = (unsigned long long*)d_ws;
    unsigned long long* boxes = (unsigned long long*)((char*)d_ws + SZ_KEYS);
    ulonglong2* cand = (ulonglong2*)((char*)d_ws + 2 * SZ_KEYS);          // 16-aligned
    unsigned* hist = (unsigned*)((char*)d_ws + 2 * SZ_KEYS + (size_t)NB * CAP * 16);
    unsigned* Tb   = hist + NB * 256;
    unsigned* cnt  = Tb + NB;
    unsigned* vcnt = cnt + NB;
    unsigned* flag = vcnt + NB;

    // zero meta (hist + Tb + cnt + vcnt + flag)
    hipMemsetAsync(hist, 0, (size_t)NB * 256 * 4 + 4 * NB * 4, stream);

    dim3 gmap((NA + 255) / 256, NB);
    k_map<<<gmap, 256, 0, stream>>>(cls, reg, anc, keys, boxes, hist, vcnt);
    k_thresh<<<1, 64, 0, stream>>>(hist, Tb);
    k_compact<<<gmap, 256, 0, stream>>>(keys, boxes, Tb, cnt, cand);
    k_nms<<<NB, 1024, 0, stream>>>(cand, cnt, Tb, vcnt, flag, out);
    k_fallback<<<NB, 1024, 0, stream>>>(keys, boxes, flag, out);
}

// Round 2
// 446.173 us; speedup vs baseline: 1.0525x; 1.0525x over previous
//
#include <hip/hip_runtime.h>

// RetinaNet decode + per-class NMS (exact reference semantics).
// Pipeline: memset(meta 96B) -> k_map (decode+select+compact) -> k_nms (sort+walk) -> k_fallback
#define NB 8
#define NA 76725
#define NC 80
#define MAXDET 100
#define CAP  1024          // compaction buffer capacity per image
#define FTHR 0x3F7FF994u   // float bits of ~0.999902: E[count]/image ~600 (max of 80 U(0,1))

__device__ inline unsigned long long shfl_down_u64(unsigned long long v, int o) {
    unsigned lo = (unsigned)v, hi = (unsigned)(v >> 32);
    lo = __shfl_down(lo, o);
    hi = __shfl_down(hi, o);
    return ((unsigned long long)hi << 32) | lo;
}

__device__ inline bool iou_ge_half(float ax1, float ay1, float ax2, float ay2, float aar,
                                   float bx1, float by1, float bx2, float by2, float bar) {
    float xx1 = fmaxf(ax1, bx1), yy1 = fmaxf(ay1, by1);
    float xx2 = fminf(ax2, bx2), yy2 = fminf(ay2, by2);
    float inter = fmaxf(xx2 - xx1, 0.0f) * fmaxf(yy2 - yy1, 0.0f);
    float un = aar + bar - inter;             // commutative add: matches ref exactly
    float iou = (un > 0.0f) ? inter / un : 0.0f;
    return iou >= 0.5f;
}

// ---- Kernel 1: per-anchor map: class max/argmax, box decode, key/box emit,
//      fixed-threshold selection + wave-aggregated compaction.
__global__ __launch_bounds__(256) void k_map(const float* __restrict__ cls,
                                             const float* __restrict__ reg,
                                             const float* __restrict__ anc,
                                             unsigned long long* __restrict__ keys,
                                             unsigned long long* __restrict__ boxes,
                                             ulonglong2* __restrict__ cand,
                                             unsigned int* __restrict__ cnt,
                                             unsigned int* __restrict__ vcnt) {
    const int b = blockIdx.y;
    const int a = blockIdx.x * 256 + threadIdx.x;

    bool valid = false, sel = false;
    unsigned long long key = 0ull, bp = 0ull;
    if (a < NA) {
        const size_t n = (size_t)b * NA + a;
        const float4* cp = reinterpret_cast<const float4*>(cls + n * NC);
        // Preload ALL 20 float4 (80 VGPRs) -> 20 independent loads in flight (MLP).
        float4 c[20];
#pragma unroll
        for (int j = 0; j < 20; ++j) c[j] = cp[j];
        float4 rg = reinterpret_cast<const float4*>(reg)[n];
        float4 an = reinterpret_cast<const float4*>(anc)[n];

        // Reduction order identical to R1 (strict > keeps first argmax; exact).
        float best = -1.0f; int bc = 0;
#pragma unroll
        for (int j = 0; j < 20; ++j) {
            float4 v = c[j];
            if (v.x > best) { best = v.x; bc = 4 * j + 0; }
            if (v.y > best) { best = v.y; bc = 4 * j + 1; }
            if (v.z > best) { best = v.z; bc = 4 * j + 2; }
            if (v.w > best) { best = v.w; bc = 4 * j + 3; }
        }

        // decode — _rn intrinsics to forbid FMA contraction (match XLA mul+add).
        // Byte-identical to R1 (verified absmax=0.0).
        float wx = __fsub_rn(an.z, an.x);
        float wy = __fsub_rn(an.w, an.y);
        float cx = __fadd_rn(an.x, __fmul_rn(0.5f, wx));
        float cy = __fadd_rn(an.y, __fmul_rn(0.5f, wy));
        float tx = __fmul_rn(rg.x, 0.1f), ty = __fmul_rn(rg.y, 0.1f);
        float tw = __fmul_rn(rg.z, 0.2f), th = __fmul_rn(rg.w, 0.2f);
        float pw = __fmul_rn(expf(tw), wx);
        float ph = __fmul_rn(expf(th), wy);
        float px = __fadd_rn(__fmul_rn(tx, wx), cx);
        float py = __fadd_rn(__fmul_rn(ty, wy), cy);
        int x1 = (int)__fsub_rn(px, __fmul_rn(0.5f, pw));
        int y1 = (int)__fsub_rn(py, __fmul_rn(0.5f, ph));
        int x2 = (int)__fadd_rn(px, __fmul_rn(0.5f, pw));
        int y2 = (int)__fadd_rn(py, __fmul_rn(0.5f, ph));
        x1 = max(x1, 0); y1 = max(y1, 0); x2 = min(x2, 639); y2 = min(y2, 639);

        bp = (unsigned long long)(unsigned short)(short)x1
           | ((unsigned long long)(unsigned short)(short)y1 << 16)
           | ((unsigned long long)(unsigned short)(short)x2 << 32)
           | ((unsigned long long)(unsigned short)(short)y2 << 48);
        if (best > 0.05f) {  // MIN_SCORE strict
            unsigned sbits = __float_as_uint(best);
            unsigned inv = 0x1FFFFu - (unsigned)a;  // index asc tie-break under desc sort
            key = ((unsigned long long)sbits << 32) | ((unsigned long long)inv << 7)
                | (unsigned)bc;
            valid = true;
            sel = sbits >= FTHR;
        }
        keys[n] = key;
        boxes[n] = bp;
    }

    const int lane = threadIdx.x & 63;
    unsigned long long bal = __ballot(valid);
    if (lane == 0 && bal) atomicAdd(&vcnt[b], (unsigned)__popcll(bal));

    unsigned long long sbal = __ballot(sel);
    unsigned base = 0;
    if (lane == 0 && sbal) base = atomicAdd(&cnt[b], (unsigned)__popcll(sbal));
    base = __shfl(base, 0);
    if (sel) {
        unsigned off = base + (unsigned)__popcll(sbal & ((1ull << lane) - 1ull));
        if (off < CAP) {
            ulonglong2 e; e.x = key; e.y = bp;
            cand[(size_t)b * CAP + off] = e;
        }
    }
}

// ---- Kernel 2: per-image bitonic sort (LDS) + greedy NMS walk + emit
__global__ __launch_bounds__(256) void k_nms(const ulonglong2* __restrict__ cand,
                                             const unsigned int* __restrict__ cnt,
                                             const unsigned int* __restrict__ vcnt,
                                             unsigned int* __restrict__ flag,
                                             float* __restrict__ out) {
    __shared__ unsigned long long sk[CAP];
    __shared__ unsigned long long sb[CAP];
    __shared__ int s_np;
    const int b = blockIdx.x;
    unsigned total = cnt[b];
    bool overflow = total > CAP;
    unsigned m = overflow ? CAP : total;

    for (int i = threadIdx.x; i < CAP; i += 256) {
        if (i < (int)m) { ulonglong2 e = cand[(size_t)b * CAP + i]; sk[i] = e.x; sb[i] = e.y; }
        else            { sk[i] = 0ull; sb[i] = 0ull; }
    }
    __syncthreads();

    // bitonic sort, descending by key
    for (int k = 2; k <= CAP; k <<= 1) {
        for (int j = k >> 1; j > 0; j >>= 1) {
            for (int i = threadIdx.x; i < CAP; i += 256) {
                int l = i ^ j;
                if (l > i) {
                    unsigned long long ki = sk[i], kl = sk[l];
                    bool desc = (i & k) == 0;
                    bool sw = desc ? (ki < kl) : (ki > kl);
                    if (sw) {
                        sk[i] = kl; sk[l] = ki;
                        unsigned long long t = sb[i]; sb[i] = sb[l]; sb[l] = t;
                    }
                }
            }
            __syncthreads();
        }
    }

    // greedy walk on wave 0; picked state distributed in registers (2 slots/lane)
    if (threadIdx.x < 64) {
        const int lane = threadIdx.x;
        float q0x1 = 0, q0y1 = 0, q0x2 = 0, q0y2 = 0, q0a = 0; int q0c = -1;
        float q1x1 = 0, q1y1 = 0, q1x2 = 0, q1y2 = 0, q1a = 0; int q1c = -1;
        int np = 0;
        for (int jj = 0; jj < (int)m && np < MAXDET; ++jj) {
            unsigned long long key = sk[jj];
            if (!key) break;
            int ci = (int)(key & 0x7Full);
            unsigned long long bx = sb[jj];
            float x1 = (float)(short)(bx & 0xFFFF);
            float y1 = (float)(short)((bx >> 16) & 0xFFFF);
            float x2 = (float)(short)((bx >> 32) & 0xFFFF);
            float y2 = (float)(short)((bx >> 48) & 0xFFFF);
            float ar = (x2 - x1) * (y2 - y1);
            bool sup = false;
            if (lane < np && q0c == ci)
                sup = iou_ge_half(q0x1, q0y1, q0x2, q0y2, q0a, x1, y1, x2, y2, ar);
            if (64 + lane < np && q1c == ci)
                sup = sup || iou_ge_half(q1x1, q1y1, q1x2, q1y2, q1a, x1, y1, x2, y2, ar);
            if (__ballot(sup) != 0ull) continue;
            int s = np;
            if (s < 64) {
                if (lane == s) {
                    q0x1 = x1; q0y1 = y1; q0x2 = x2; q0y2 = y2; q0a = ar; q0c = ci;
                    out[b * MAXDET + s] = __uint_as_float((unsigned)(key >> 32));
                    out[NB * MAXDET + b * MAXDET + s] = (float)ci;
                    float* ob = out + 2 * NB * MAXDET + (size_t)(b * MAXDET + s) * 4;
                    ob[0] = x1; ob[1] = y1; ob[2] = x2; ob[3] = y2;
                }
            } else {
                if (lane == s - 64) {
                    q1x1 = x1; q1y1 = y1; q1x2 = x2; q1y2 = y2; q1a = ar; q1c = ci;
                    out[b * MAXDET + s] = __uint_as_float((unsigned)(key >> 32));
                    out[NB * MAXDET + b * MAXDET + s] = (float)ci;
                    float* ob = out + 2 * NB * MAXDET + (size_t)(b * MAXDET + s) * 4;
                    ob[0] = x1; ob[1] = y1; ob[2] = x2; ob[3] = y2;
                }
            }
            ++np;
        }
        if (lane == 0) s_np = np;
    }
    __syncthreads();
    int np = s_np;
    // fallback iff candidates were dropped (overflow) or walk exhausted with unseen valid cands
    bool fb = overflow || (np < MAXDET && vcnt[b] > m);
    if (threadIdx.x == 0) flag[b] = fb ? 1u : 0u;
    if (!fb) {
        for (int i = np + (int)threadIdx.x; i < MAXDET; i += 256) {
            out[b * MAXDET + i] = -1.0f;
            out[NB * MAXDET + b * MAXDET + i] = -1.0f;
            float* ob = out + 2 * NB * MAXDET + (size_t)(b * MAXDET + i) * 4;
            ob[0] = -1.0f; ob[1] = -1.0f; ob[2] = -1.0f; ob[3] = -1.0f;
        }
    }
}

// ---- Kernel 3: exact slow fallback (reference algorithm); no-op unless flag[b]
__global__ __launch_bounds__(1024) void k_fallback(unsigned long long* __restrict__ keys,
                                                   const unsigned long long* __restrict__ boxes,
                                                   const unsigned int* __restrict__ flag,
                                                   float* __restrict__ out) {
    const int b = blockIdx.x;
    if (!flag[b]) return;
    __shared__ unsigned long long wm[16];
    __shared__ unsigned long long gbest;
    unsigned long long* kb = keys + (size_t)b * NA;
    const unsigned long long* bb = boxes + (size_t)b * NA;

    for (int it = 0; it < MAXDET; ++it) {
        unsigned long long best = 0ull;
        for (int i = threadIdx.x; i < NA; i += 1024) {
            unsigned long long k = kb[i];
            if (k > best) best = k;
        }
        for (int o = 32; o > 0; o >>= 1) {
            unsigned long long v = shfl_down_u64(best, o);
            if (v > best) best = v;
        }
        if ((threadIdx.x & 63) == 0) wm[threadIdx.x >> 6] = best;
        __syncthreads();
        if (threadIdx.x == 0) {
            unsigned long long g = wm[0];
            for (int w = 1; w < 16; ++w) if (wm[w] > g) g = wm[w];
            gbest = g;
        }
        __syncthreads();
        best = gbest;
        if (best == 0ull) {
            for (int s = it + (int)threadIdx.x; s < MAXDET; s += 1024) {
                out[b * MAXDET + s] = -1.0f;
                out[NB * MAXDET + b * MAXDET + s] = -1.0f;
                float* ob = out + 2 * NB * MAXDET + (size_t)(b * MAXDET + s) * 4;
                ob[0] = -1.0f; ob[1] = -1.0f; ob[2] = -1.0f; ob[3] = -1.0f;
            }
            break;
        }
        int ci = (int)(best & 0x7Full);
        int a = 0x1FFFF - (int)((best >> 7) & 0x1FFFFull);
        unsigned long long bx = bb[a];
        float x1 = (float)(short)(bx & 0xFFFF);
        float y1 = (float)(short)((bx >> 16) & 0xFFFF);
        float x2 = (float)(short)((bx >> 32) & 0xFFFF);
        float y2 = (float)(short)((bx >> 48) & 0xFFFF);
        float ar = (x2 - x1) * (y2 - y1);
        if (threadIdx.x == 0) {
            out[b * MAXDET + it] = __uint_as_float((unsigned)(best >> 32));
            out[NB * MAXDET + b * MAXDET + it] = (float)ci;
            float* ob = out + 2 * NB * MAXDET + (size_t)(b * MAXDET + it) * 4;
            ob[0] = x1; ob[1] = y1; ob[2] = x2; ob[3] = y2;
        }
        for (int i = threadIdx.x; i < NA; i += 1024) {
            unsigned long long kk = kb[i];
            if (!kk) continue;
            if (kk == best) { kb[i] = 0ull; continue; }
            if ((int)(kk & 0x7Full) != ci) continue;
            unsigned long long ob2 = bb[i];
            float u1 = (float)(short)(ob2 & 0xFFFF);
            float v1 = (float)(short)((ob2 >> 16) & 0xFFFF);
            float u2 = (float)(short)((ob2 >> 32) & 0xFFFF);
            float v2 = (float)(short)((ob2 >> 48) & 0xFFFF);
            float oar = (u2 - u1) * (v2 - v1);
            if (iou_ge_half(x1, y1, x2, y2, ar, u1, v1, u2, v2, oar)) kb[i] = 0ull;
        }
        __syncthreads();
    }
}

extern "C" void kernel_launch(void* const* d_in, const int* in_sizes, int n_in,
                              void* d_out, int out_size, void* d_ws, size_t ws_size,
                              hipStream_t stream) {
    const float* cls = (const float*)d_in[0];
    const float* reg = (const float*)d_in[1];
    const float* anc = (const float*)d_in[2];
    float* out = (float*)d_out;

    const size_t SZ_KEYS = (size_t)NB * NA * 8;               // 4,910,400 B
    unsigned long long* keys  = (unsigned long long*)d_ws;
    unsigned long long* boxes = (unsigned long long*)((char*)d_ws + SZ_KEYS);
    ulonglong2* cand = (ulonglong2*)((char*)d_ws + 2 * SZ_KEYS);          // 16-aligned
    unsigned* cnt  = (unsigned*)((char*)d_ws + 2 * SZ_KEYS + (size_t)NB * CAP * 16);
    unsigned* vcnt = cnt + NB;
    unsigned* flag = vcnt + NB;

    // zero meta (cnt + vcnt + flag = 96 B)
    hipMemsetAsync(cnt, 0, 3 * NB * 4, stream);

    dim3 gmap((NA + 255) / 256, NB);
    k_map<<<gmap, 256, 0, stream>>>(cls, reg, anc, keys, boxes, cand, cnt, vcnt);
    k_nms<<<NB, 256, 0, stream>>>(cand, cnt, vcnt, flag, out);
    k_fallback<<<NB, 1024, 0, stream>>>(keys, boxes, flag, out);
}